// Round 13
// baseline (573.570 us; speedup 1.0000x reference)
//
#include <hip/hip_runtime.h>
#include <math.h>

#define F 256
#define E 256
#define S 32
#define CH 4
#define NGRID 768   // 3 blocks/CU x 256 CUs -> all resident (launch_bounds(256,3))
#define QVB 626     // gemm virtual blocks: 313 x 2
#define GVB 2500    // gather virtual blocks: 10000/4

typedef __attribute__((ext_vector_type(8))) short short8;
typedef __attribute__((ext_vector_type(4))) float f32x4;

__device__ __forceinline__ ushort f2bf(float x) {
    uint u = __float_as_uint(x);
    return (ushort)((u + 0x7fffu + ((u >> 16) & 1u)) >> 16);
}
__device__ __forceinline__ float bf2f(ushort h) {
    return __uint_as_float(((uint)h) << 16);
}
__device__ __forceinline__ uint4 pack8(const ushort* h) {
    uint4 r;
    r.x = (uint)h[0] | ((uint)h[1] << 16); r.y = (uint)h[2] | ((uint)h[3] << 16);
    r.z = (uint)h[4] | ((uint)h[5] << 16); r.w = (uint)h[6] | ((uint)h[7] << 16);
    return r;
}
__device__ __forceinline__ void split4(const float* x, uint2& ph, uint2& pl) {
    ushort h[4], l[4];
#pragma unroll
    for (int i = 0; i < 4; ++i) { h[i] = f2bf(x[i]); l[i] = f2bf(x[i] - bf2f(h[i])); }
    ph.x = (uint)h[0] | ((uint)h[1] << 16); ph.y = (uint)h[2] | ((uint)h[3] << 16);
    pl.x = (uint)l[0] | ((uint)l[1] << 16); pl.y = (uint)l[2] | ((uint)l[3] << 16);
}
__device__ __forceinline__ void split8(const float* x, short8& h, short8& l) {
    ushort hh[8], ll[8];
#pragma unroll
    for (int i = 0; i < 8; ++i) { hh[i] = f2bf(x[i]); ll[i] = f2bf(x[i] - bf2f(hh[i])); }
    uint4 ph = pack8(hh), pl = pack8(ll);
    h = *reinterpret_cast<short8*>(&ph);
    l = *reinterpret_cast<short8*>(&pl);
}

// ---------------------------------------------------------------------------
// software grid barrier: one dedicated counter per phase boundary (no reset,
// no generation races). Arrive with ACQ_REL (flushes this XCD's dirty L2),
// spin with ACQUIRE (invalidates stale lines) -> cross-XCD visibility (G16).
// Every block MUST reach every barrier (no early returns anywhere).
// ---------------------------------------------------------------------------
__device__ __forceinline__ void gbar(uint* ctr) {
    __syncthreads();
    if (threadIdx.x == 0) {
        __threadfence();
        __hip_atomic_fetch_add(ctr, 1u, __ATOMIC_ACQ_REL, __HIP_MEMORY_SCOPE_AGENT);
        while (__hip_atomic_load(ctr, __ATOMIC_ACQUIRE, __HIP_MEMORY_SCOPE_AGENT)
               < (uint)NGRID)
            __builtin_amdgcn_s_sleep(8);
    }
    __syncthreads();
}

// ---------------------------------------------------------------------------
// gather helpers (proven online-softmax config, R3)
// ---------------------------------------------------------------------------
__device__ __forceinline__ void ld_chunk(float4* d, int idxv, int s0,
                                         const float* __restrict__ t, int lane) {
#pragma unroll
    for (int j = 0; j < CH; ++j) {
        const int nid = __builtin_amdgcn_readlane(idxv, s0 + j);
        d[j] = *reinterpret_cast<const float4*>(&t[(size_t)nid * F + lane * 4]);
    }
}
__device__ __forceinline__ void proc_chunk(const float4* v, const float4 qv,
                                           float& m, float& l, float4& acc) {
#pragma unroll
    for (int j = 0; j < CH; ++j) {
        float p = v[j].x * qv.x + v[j].y * qv.y + v[j].z * qv.z + v[j].w * qv.w;
#pragma unroll
        for (int off = 32; off; off >>= 1) p += __shfl_xor(p, off);
        if (p <= m) {
            const float w = __expf(p - m);
            l += w;
            acc.x += w * v[j].x; acc.y += w * v[j].y;
            acc.z += w * v[j].z; acc.w += w * v[j].w;
        } else {
            const float cc = __expf(m - p);
            l = l * cc + 1.f;
            acc.x = acc.x * cc + v[j].x; acc.y = acc.y * cc + v[j].y;
            acc.z = acc.z * cc + v[j].z; acc.w = acc.w * cc + v[j].w;
            m = p;
        }
    }
}

// ---------------------------------------------------------------------------
// gemm virtual-block body (proven R10/R11 gemm32 geometry: BM=32, BN=128,
// BK=32, 4 waves; A dbuf in LDS, B fragments straight from split tables).
// ---------------------------------------------------------------------------
__device__ __forceinline__ void gemm_vb(int vb, const float* __restrict__ X,
                                        const int* __restrict__ idx,
                                        const ushort* __restrict__ BTh,
                                        const ushort* __restrict__ BTl,
                                        const float* __restrict__ bias,
                                        float* __restrict__ outp, int rows,
                                        char* smem, int tid, int wave,
                                        int fr, int fk) {
    ushort (*Ah)[32][40] = (ushort(*)[32][40])smem;
    ushort (*Al)[32][40] = (ushort(*)[32][40])(smem + 5120);

    const int bx = vb % 313, by = vb / 313;
    const int row0 = bx * 32;
    const int col0 = by * 128 + wave * 32;

    const int arL = tid >> 3, akL = (tid & 7) * 4;
    const int gr = row0 + arL;
    const int grc = gr < rows ? gr : rows - 1;
    const long arow = idx ? (long)idx[grc] : (long)grc;
    const float* aptr = X + arow * (long)F + akL;

    f32x4 acc[2][2];
#pragma unroll
    for (int m = 0; m < 2; ++m)
#pragma unroll
        for (int n = 0; n < 2; ++n) acc[m][n] = (f32x4){0.f, 0.f, 0.f, 0.f};

    {
        const float4 av = *reinterpret_cast<const float4*>(aptr);
        uint2 h, l; split4(&av.x, h, l);
        *reinterpret_cast<uint2*>(&Ah[0][arL][akL]) = h;
        *reinterpret_cast<uint2*>(&Al[0][arL][akL]) = l;
    }
    __syncthreads();

    for (int t = 0; t < 8; ++t) {
        const int cur = t & 1;
        float4 nv;
        if (t < 7) nv = *reinterpret_cast<const float4*>(aptr + (t + 1) * 32);

        short8 a_h[2], a_l[2];
#pragma unroll
        for (int m = 0; m < 2; ++m) {
            a_h[m] = *reinterpret_cast<const short8*>(&Ah[cur][m * 16 + fr][fk * 8]);
            a_l[m] = *reinterpret_cast<const short8*>(&Al[cur][m * 16 + fr][fk * 8]);
        }
#pragma unroll
        for (int n = 0; n < 2; ++n) {
            const size_t boff = (size_t)(col0 + n * 16 + fr) * F + t * 32 + fk * 8;
            const short8 bh = *reinterpret_cast<const short8*>(&BTh[boff]);
            const short8 bl = *reinterpret_cast<const short8*>(&BTl[boff]);
#pragma unroll
            for (int m = 0; m < 2; ++m) {
                acc[m][n] = __builtin_amdgcn_mfma_f32_16x16x32_bf16(a_h[m], bh, acc[m][n], 0, 0, 0);
                acc[m][n] = __builtin_amdgcn_mfma_f32_16x16x32_bf16(a_h[m], bl, acc[m][n], 0, 0, 0);
                acc[m][n] = __builtin_amdgcn_mfma_f32_16x16x32_bf16(a_l[m], bh, acc[m][n], 0, 0, 0);
            }
        }
        if (t < 7) {
            uint2 h, l; split4(&nv.x, h, l);
            *reinterpret_cast<uint2*>(&Ah[cur ^ 1][arL][akL]) = h;
            *reinterpret_cast<uint2*>(&Al[cur ^ 1][arL][akL]) = l;
        }
        __syncthreads();
    }

#pragma unroll
    for (int n = 0; n < 2; ++n) {
        const int col = col0 + n * 16 + fr;
        const float cc = bias[col];
#pragma unroll
        for (int m = 0; m < 2; ++m)
#pragma unroll
            for (int r = 0; r < 4; ++r) {
                const int row = row0 + m * 16 + fk * 4 + r;
                if (row < rows) outp[(size_t)row * F + col] = acc[m][n][r] + cc;
            }
    }
}

// ---------------------------------------------------------------------------
// pipeline: single plain-launch persistent kernel, 768 blocks x 256 thr,
// phases separated by software grid barriers. Each phase grid-strides its
// proven virtual-block config.
// ---------------------------------------------------------------------------
__global__ __launch_bounds__(256, 3) void pipeline(const int* __restrict__ nodes,
                                                   const int* __restrict__ neigh,
                                                   const float* __restrict__ id2feat,
                                                   const float* __restrict__ Wq,
                                                   const float* __restrict__ bq,
                                                   const float* __restrict__ Wk,
                                                   const float* __restrict__ Wv,
                                                   const float* __restrict__ bv,
                                                   float* __restrict__ out,
                                                   uint* __restrict__ bar,
                                                   ushort* __restrict__ MTh,
                                                   ushort* __restrict__ MTl,
                                                   ushort* __restrict__ WvTh,
                                                   ushort* __restrict__ WvTl,
                                                   float* __restrict__ cbuf,
                                                   float* __restrict__ qtm,
                                                   int B) {
    __shared__ __align__(16) char smem[16640];
    const int tid = threadIdx.x, lane = tid & 63, wave = tid >> 6;
    const int fr = lane & 15, fk = lane >> 4;
    const int pb = blockIdx.x;

    // ---------------- phase 0: prep (blocks 0..31) ----------------
    if (pb < 8) {
        // MT[j][i] = Wk_j . Wq_i (bf16x3), 32 j-rows/block, wn = wave
        const int j0 = (pb >> 1) * 64, wm = pb & 1, wn = wave;
        f32x4 acc[2][4];
#pragma unroll
        for (int m = 0; m < 2; ++m)
#pragma unroll
            for (int n = 0; n < 4; ++n) acc[m][n] = (f32x4){0.f, 0.f, 0.f, 0.f};
        for (int k0 = 0; k0 < F; k0 += 32) {
            short8 ah[2], al[2];
#pragma unroll
            for (int m = 0; m < 2; ++m) {
                const float* p = &Wk[(size_t)(j0 + wm * 32 + m * 16 + fr) * F + k0 + fk * 8];
                float x[8];
                *reinterpret_cast<float4*>(&x[0]) = *reinterpret_cast<const float4*>(p);
                *reinterpret_cast<float4*>(&x[4]) = *reinterpret_cast<const float4*>(p + 4);
                split8(x, ah[m], al[m]);
            }
#pragma unroll
            for (int n = 0; n < 4; ++n) {
                const float* p = &Wq[(size_t)(wn * 64 + n * 16 + fr) * F + k0 + fk * 8];
                float x[8];
                *reinterpret_cast<float4*>(&x[0]) = *reinterpret_cast<const float4*>(p);
                *reinterpret_cast<float4*>(&x[4]) = *reinterpret_cast<const float4*>(p + 4);
                short8 bh, bl;
                split8(x, bh, bl);
#pragma unroll
                for (int m = 0; m < 2; ++m) {
                    acc[m][n] = __builtin_amdgcn_mfma_f32_16x16x32_bf16(ah[m], bh, acc[m][n], 0, 0, 0);
                    acc[m][n] = __builtin_amdgcn_mfma_f32_16x16x32_bf16(ah[m], bl, acc[m][n], 0, 0, 0);
                    acc[m][n] = __builtin_amdgcn_mfma_f32_16x16x32_bf16(al[m], bh, acc[m][n], 0, 0, 0);
                }
            }
        }
#pragma unroll
        for (int n = 0; n < 4; ++n) {
            const int i = wn * 64 + n * 16 + fr;
#pragma unroll
            for (int m = 0; m < 2; ++m)
#pragma unroll
                for (int r = 0; r < 4; ++r) {
                    const int j = j0 + wm * 32 + m * 16 + fk * 4 + r;
                    const float v = acc[m][n][r];
                    const ushort h = f2bf(v);
                    MTh[(size_t)j * F + i] = h;
                    MTl[(size_t)j * F + i] = f2bf(v - bf2f(h));
                }
        }
    } else if (pb < 24) {
        // WvT[j][k] = Wv[k][j], split hi/lo (64x64 LDS transpose, 256 thr)
        float (*t)[65] = (float(*)[65])smem;
        const int tb = pb - 8;
        const int jt = (tb & 3) * 64, kt = (tb >> 2) * 64;
        const int lkb = tid >> 3, lj = (tid & 7) * 8;
#pragma unroll
        for (int u2 = 0; u2 < 2; ++u2) {
            const int lk = lkb + u2 * 32;
            const float* p = &Wv[(size_t)(kt + lk) * E + jt + lj];
            const float4 v0 = *reinterpret_cast<const float4*>(p);
            const float4 v1 = *reinterpret_cast<const float4*>(p + 4);
            t[lk][lj + 0] = v0.x; t[lk][lj + 1] = v0.y; t[lk][lj + 2] = v0.z; t[lk][lj + 3] = v0.w;
            t[lk][lj + 4] = v1.x; t[lk][lj + 5] = v1.y; t[lk][lj + 6] = v1.z; t[lk][lj + 7] = v1.w;
        }
        __syncthreads();
#pragma unroll
        for (int u2 = 0; u2 < 2; ++u2) {
            const int oj = lkb + u2 * 32;
            const int ok = lj;
            ushort h[8], l[8];
#pragma unroll
            for (int u = 0; u < 8; ++u) {
                const float v = t[ok + u][oj];
                h[u] = f2bf(v); l[u] = f2bf(v - bf2f(h[u]));
            }
            *reinterpret_cast<uint4*>(&WvTh[(size_t)(jt + oj) * F + kt + ok]) = pack8(h);
            *reinterpret_cast<uint4*>(&WvTl[(size_t)(jt + oj) * F + kt + ok]) = pack8(l);
        }
    } else if (pb < 32) {
        // c[j] = Wk_j . bq (32 j per block)
        float* bqs = (float*)smem;
        bqs[tid] = bq[tid];
        __syncthreads();
        const float4 b4 = *reinterpret_cast<const float4*>(&bqs[lane * 4]);
#pragma unroll
        for (int i = 0; i < 8; ++i) {
            const int j = (pb - 24) * 32 + wave * 8 + i;
            const float4 k4 = *reinterpret_cast<const float4*>(&Wk[(size_t)j * F + lane * 4]);
            float p = k4.x * b4.x + k4.y * b4.y + k4.z * b4.z + k4.w * b4.w;
#pragma unroll
            for (int off = 32; off; off >>= 1) p += __shfl_xor(p, off);
            if (lane == 0) cbuf[j] = p;
        }
    }
    gbar(&bar[0]);

    // ---------------- phase 1: q~ = gather @ MT + c ----------------
    for (int vb = pb; vb < QVB; vb += NGRID)
        gemm_vb(vb, id2feat, nodes, MTh, MTl, cbuf, qtm, B, smem, tid, wave, fr, fk);
    gbar(&bar[1]);

    // ---------------- phase 2: gather (proven config, triple-buffered:
    //                  12 row-loads in flight to offset 12-vs-19.5 waves/CU) --
    for (int vb = pb; vb < GVB; vb += NGRID) {
        const int node = vb * 4 + wave;
        if (node < B) {
            const int idxv = neigh[node * S + (lane & (S - 1))];
            const float4 qv = *reinterpret_cast<const float4*>(&qtm[(size_t)node * F + lane * 4]);
            float m = -INFINITY, l = 0.f;
            float4 a = make_float4(0.f, 0.f, 0.f, 0.f);
            float4 va[CH], vb2[CH], vc[CH];
            ld_chunk(va, idxv, 0, id2feat, lane);
            ld_chunk(vb2, idxv, 4, id2feat, lane);
            ld_chunk(vc, idxv, 8, id2feat, lane);
            proc_chunk(va, qv, m, l, a);
            ld_chunk(va, idxv, 12, id2feat, lane);
            proc_chunk(vb2, qv, m, l, a);
            ld_chunk(vb2, idxv, 16, id2feat, lane);
            proc_chunk(vc, qv, m, l, a);
            ld_chunk(vc, idxv, 20, id2feat, lane);
            proc_chunk(va, qv, m, l, a);
            ld_chunk(va, idxv, 24, id2feat, lane);
            proc_chunk(vb2, qv, m, l, a);
            ld_chunk(vb2, idxv, 28, id2feat, lane);
            proc_chunk(vc, qv, m, l, a);
            proc_chunk(va, qv, m, l, a);
            proc_chunk(vb2, qv, m, l, a);
            const float inv = 1.0f / l;
            float4 o;
            o.x = a.x * inv; o.y = a.y * inv; o.z = a.z * inv; o.w = a.w * inv;
            *reinterpret_cast<float4*>(&qtm[(size_t)node * F + lane * 4]) = o;
        }
    }
    gbar(&bar[2]);

    // ---------------- phase 3: out = m @ WvT + bv ----------------
    for (int vb = pb; vb < QVB; vb += NGRID)
        gemm_vb(vb, qtm, nullptr, WvTh, WvTl, bv, out, B, smem, tid, wave, fr, fk);
}

// ---------------------------------------------------------------------------
extern "C" void kernel_launch(void* const* d_in, const int* in_sizes, int n_in,
                              void* d_out, int out_size, void* d_ws, size_t ws_size,
                              hipStream_t stream) {
    const int*   nodes   = (const int*)d_in[0];
    const int*   neigh   = (const int*)d_in[1];
    const float* id2feat = (const float*)d_in[2];
    const float* Wq      = (const float*)d_in[3];
    const float* bq      = (const float*)d_in[4];
    const float* Wk      = (const float*)d_in[5];
    // d_in[6] = bk unused: softmax-invariant (self column masked).
    const float* Wv      = (const float*)d_in[7];
    const float* bv      = (const float*)d_in[8];
    float* out = (float*)d_out;
    int B = in_sizes[0];

    // workspace layout: [barriers 64B][MTh][MTl][WvTh][WvTl][cbuf][qtm]
    uint*   bar  = (uint*)d_ws;
    ushort* MTh  = (ushort*)((char*)d_ws + 64);
    ushort* MTl  = MTh + 65536;
    ushort* WvTh = MTl + 65536;
    ushort* WvTl = WvTh + 65536;
    float*  cbuf = (float*)(WvTl + 65536);
    float*  qtm  = cbuf + 256;

    // zero the barrier counters (fresh every launch; graph-capture legal)
    hipMemsetAsync(bar, 0, 64, stream);
    pipeline<<<dim3(NGRID), dim3(256), 0, stream>>>(nodes, neigh, id2feat,
                                                    Wq, bq, Wk, Wv, bv, out,
                                                    bar, MTh, MTl, WvTh, WvTl,
                                                    cbuf, qtm, B);
}

// Round 14
// 369.502 us; speedup vs baseline: 1.5523x; 1.5523x over previous
//
#include <hip/hip_runtime.h>
#include <math.h>

#define F 256
#define E 256
#define S 32
#define CH 4
#define NGRID 768   // 3 blocks/CU x 256 CUs -> all resident (launch_bounds(256,3))
#define QVB 626     // gemm virtual blocks: 313 x 2
#define GVB 2500    // gather virtual blocks: 10000/4

typedef __attribute__((ext_vector_type(8))) short short8;
typedef __attribute__((ext_vector_type(4))) float f32x4;

__device__ __forceinline__ ushort f2bf(float x) {
    uint u = __float_as_uint(x);
    return (ushort)((u + 0x7fffu + ((u >> 16) & 1u)) >> 16);
}
__device__ __forceinline__ float bf2f(ushort h) {
    return __uint_as_float(((uint)h) << 16);
}
__device__ __forceinline__ uint4 pack8(const ushort* h) {
    uint4 r;
    r.x = (uint)h[0] | ((uint)h[1] << 16); r.y = (uint)h[2] | ((uint)h[3] << 16);
    r.z = (uint)h[4] | ((uint)h[5] << 16); r.w = (uint)h[6] | ((uint)h[7] << 16);
    return r;
}
__device__ __forceinline__ void split4(const float* x, uint2& ph, uint2& pl) {
    ushort h[4], l[4];
#pragma unroll
    for (int i = 0; i < 4; ++i) { h[i] = f2bf(x[i]); l[i] = f2bf(x[i] - bf2f(h[i])); }
    ph.x = (uint)h[0] | ((uint)h[1] << 16); ph.y = (uint)h[2] | ((uint)h[3] << 16);
    pl.x = (uint)l[0] | ((uint)l[1] << 16); pl.y = (uint)l[2] | ((uint)l[3] << 16);
}
__device__ __forceinline__ void split8(const float* x, short8& h, short8& l) {
    ushort hh[8], ll[8];
#pragma unroll
    for (int i = 0; i < 8; ++i) { hh[i] = f2bf(x[i]); ll[i] = f2bf(x[i] - bf2f(hh[i])); }
    uint4 ph = pack8(hh), pl = pack8(ll);
    h = *reinterpret_cast<short8*>(&ph);
    l = *reinterpret_cast<short8*>(&pl);
}

// ---------------------------------------------------------------------------
// software grid barrier, FIXED (R13 post-mortem): spin with RELAXED atomic
// loads (performed at the coherence point -> sees remote updates, emits NO
// cache invalidates), then ONE acquire load after exit for the cross-XCD
// invalidate (G16). R13's acquire-per-spin-iteration invalidate storm was
// the 5x slowdown. Release side: __threadfence + RELEASE add (L2 writeback).
// One dedicated counter per boundary; every block reaches every barrier.
// ---------------------------------------------------------------------------
__device__ __forceinline__ void gbar(uint* ctr) {
    __syncthreads();
    if (threadIdx.x == 0) {
        __threadfence();
        __hip_atomic_fetch_add(ctr, 1u, __ATOMIC_RELEASE, __HIP_MEMORY_SCOPE_AGENT);
        while (__hip_atomic_load(ctr, __ATOMIC_RELAXED, __HIP_MEMORY_SCOPE_AGENT)
               < (uint)NGRID)
            __builtin_amdgcn_s_sleep(16);
        (void)__hip_atomic_load(ctr, __ATOMIC_ACQUIRE, __HIP_MEMORY_SCOPE_AGENT);
    }
    __syncthreads();
}

// ---------------------------------------------------------------------------
// gather helpers (proven online-softmax config, R3)
// ---------------------------------------------------------------------------
__device__ __forceinline__ void ld_chunk(float4* d, int idxv, int s0,
                                         const float* __restrict__ t, int lane) {
#pragma unroll
    for (int j = 0; j < CH; ++j) {
        const int nid = __builtin_amdgcn_readlane(idxv, s0 + j);
        d[j] = *reinterpret_cast<const float4*>(&t[(size_t)nid * F + lane * 4]);
    }
}
__device__ __forceinline__ void proc_chunk(const float4* v, const float4 qv,
                                           float& m, float& l, float4& acc) {
#pragma unroll
    for (int j = 0; j < CH; ++j) {
        float p = v[j].x * qv.x + v[j].y * qv.y + v[j].z * qv.z + v[j].w * qv.w;
#pragma unroll
        for (int off = 32; off; off >>= 1) p += __shfl_xor(p, off);
        if (p <= m) {
            const float w = __expf(p - m);
            l += w;
            acc.x += w * v[j].x; acc.y += w * v[j].y;
            acc.z += w * v[j].z; acc.w += w * v[j].w;
        } else {
            const float cc = __expf(m - p);
            l = l * cc + 1.f;
            acc.x = acc.x * cc + v[j].x; acc.y = acc.y * cc + v[j].y;
            acc.z = acc.z * cc + v[j].z; acc.w = acc.w * cc + v[j].w;
            m = p;
        }
    }
}

// ---------------------------------------------------------------------------
// gemm virtual-block body (proven R10/R11 gemm32 geometry: BM=32, BN=128,
// BK=32, 4 waves; A dbuf in LDS, B fragments straight from split tables).
// ---------------------------------------------------------------------------
__device__ __forceinline__ void gemm_vb(int vb, const float* __restrict__ X,
                                        const int* __restrict__ idx,
                                        const ushort* __restrict__ BTh,
                                        const ushort* __restrict__ BTl,
                                        const float* __restrict__ bias,
                                        float* __restrict__ outp, int rows,
                                        char* smem, int tid, int wave,
                                        int fr, int fk) {
    ushort (*Ah)[32][40] = (ushort(*)[32][40])smem;
    ushort (*Al)[32][40] = (ushort(*)[32][40])(smem + 5120);

    const int bx = vb % 313, by = vb / 313;
    const int row0 = bx * 32;
    const int col0 = by * 128 + wave * 32;

    const int arL = tid >> 3, akL = (tid & 7) * 4;
    const int gr = row0 + arL;
    const int grc = gr < rows ? gr : rows - 1;
    const long arow = idx ? (long)idx[grc] : (long)grc;
    const float* aptr = X + arow * (long)F + akL;

    f32x4 acc[2][2];
#pragma unroll
    for (int m = 0; m < 2; ++m)
#pragma unroll
        for (int n = 0; n < 2; ++n) acc[m][n] = (f32x4){0.f, 0.f, 0.f, 0.f};

    {
        const float4 av = *reinterpret_cast<const float4*>(aptr);
        uint2 h, l; split4(&av.x, h, l);
        *reinterpret_cast<uint2*>(&Ah[0][arL][akL]) = h;
        *reinterpret_cast<uint2*>(&Al[0][arL][akL]) = l;
    }
    __syncthreads();

    for (int t = 0; t < 8; ++t) {
        const int cur = t & 1;
        float4 nv;
        if (t < 7) nv = *reinterpret_cast<const float4*>(aptr + (t + 1) * 32);

        short8 a_h[2], a_l[2];
#pragma unroll
        for (int m = 0; m < 2; ++m) {
            a_h[m] = *reinterpret_cast<const short8*>(&Ah[cur][m * 16 + fr][fk * 8]);
            a_l[m] = *reinterpret_cast<const short8*>(&Al[cur][m * 16 + fr][fk * 8]);
        }
#pragma unroll
        for (int n = 0; n < 2; ++n) {
            const size_t boff = (size_t)(col0 + n * 16 + fr) * F + t * 32 + fk * 8;
            const short8 bh = *reinterpret_cast<const short8*>(&BTh[boff]);
            const short8 bl = *reinterpret_cast<const short8*>(&BTl[boff]);
#pragma unroll
            for (int m = 0; m < 2; ++m) {
                acc[m][n] = __builtin_amdgcn_mfma_f32_16x16x32_bf16(a_h[m], bh, acc[m][n], 0, 0, 0);
                acc[m][n] = __builtin_amdgcn_mfma_f32_16x16x32_bf16(a_h[m], bl, acc[m][n], 0, 0, 0);
                acc[m][n] = __builtin_amdgcn_mfma_f32_16x16x32_bf16(a_l[m], bh, acc[m][n], 0, 0, 0);
            }
        }
        if (t < 7) {
            uint2 h, l; split4(&nv.x, h, l);
            *reinterpret_cast<uint2*>(&Ah[cur ^ 1][arL][akL]) = h;
            *reinterpret_cast<uint2*>(&Al[cur ^ 1][arL][akL]) = l;
        }
        __syncthreads();
    }

#pragma unroll
    for (int n = 0; n < 2; ++n) {
        const int col = col0 + n * 16 + fr;
        const float cc = bias[col];
#pragma unroll
        for (int m = 0; m < 2; ++m)
#pragma unroll
            for (int r = 0; r < 4; ++r) {
                const int row = row0 + m * 16 + fk * 4 + r;
                if (row < rows) outp[(size_t)row * F + col] = acc[m][n][r] + cc;
            }
    }
}

// ---------------------------------------------------------------------------
// pipeline: single plain-launch persistent kernel, 768 blocks x 256 thr,
// phases separated by relaxed-spin software grid barriers. Each phase
// grid-strides its proven virtual-block config.
// ---------------------------------------------------------------------------
__global__ __launch_bounds__(256, 3) void pipeline(const int* __restrict__ nodes,
                                                   const int* __restrict__ neigh,
                                                   const float* __restrict__ id2feat,
                                                   const float* __restrict__ Wq,
                                                   const float* __restrict__ bq,
                                                   const float* __restrict__ Wk,
                                                   const float* __restrict__ Wv,
                                                   const float* __restrict__ bv,
                                                   float* __restrict__ out,
                                                   uint* __restrict__ bar,
                                                   ushort* __restrict__ MTh,
                                                   ushort* __restrict__ MTl,
                                                   ushort* __restrict__ WvTh,
                                                   ushort* __restrict__ WvTl,
                                                   float* __restrict__ cbuf,
                                                   float* __restrict__ qtm,
                                                   int B) {
    __shared__ __align__(16) char smem[16640];
    const int tid = threadIdx.x, lane = tid & 63, wave = tid >> 6;
    const int fr = lane & 15, fk = lane >> 4;
    const int pb = blockIdx.x;

    // ---------------- phase 0: prep (blocks 0..31) ----------------
    if (pb < 8) {
        // MT[j][i] = Wk_j . Wq_i (bf16x3), 32 j-rows/block, wn = wave
        const int j0 = (pb >> 1) * 64, wm = pb & 1, wn = wave;
        f32x4 acc[2][4];
#pragma unroll
        for (int m = 0; m < 2; ++m)
#pragma unroll
            for (int n = 0; n < 4; ++n) acc[m][n] = (f32x4){0.f, 0.f, 0.f, 0.f};
        for (int k0 = 0; k0 < F; k0 += 32) {
            short8 ah[2], al[2];
#pragma unroll
            for (int m = 0; m < 2; ++m) {
                const float* p = &Wk[(size_t)(j0 + wm * 32 + m * 16 + fr) * F + k0 + fk * 8];
                float x[8];
                *reinterpret_cast<float4*>(&x[0]) = *reinterpret_cast<const float4*>(p);
                *reinterpret_cast<float4*>(&x[4]) = *reinterpret_cast<const float4*>(p + 4);
                split8(x, ah[m], al[m]);
            }
#pragma unroll
            for (int n = 0; n < 4; ++n) {
                const float* p = &Wq[(size_t)(wn * 64 + n * 16 + fr) * F + k0 + fk * 8];
                float x[8];
                *reinterpret_cast<float4*>(&x[0]) = *reinterpret_cast<const float4*>(p);
                *reinterpret_cast<float4*>(&x[4]) = *reinterpret_cast<const float4*>(p + 4);
                short8 bh, bl;
                split8(x, bh, bl);
#pragma unroll
                for (int m = 0; m < 2; ++m) {
                    acc[m][n] = __builtin_amdgcn_mfma_f32_16x16x32_bf16(ah[m], bh, acc[m][n], 0, 0, 0);
                    acc[m][n] = __builtin_amdgcn_mfma_f32_16x16x32_bf16(ah[m], bl, acc[m][n], 0, 0, 0);
                    acc[m][n] = __builtin_amdgcn_mfma_f32_16x16x32_bf16(al[m], bh, acc[m][n], 0, 0, 0);
                }
            }
        }
#pragma unroll
        for (int n = 0; n < 4; ++n) {
            const int i = wn * 64 + n * 16 + fr;
#pragma unroll
            for (int m = 0; m < 2; ++m)
#pragma unroll
                for (int r = 0; r < 4; ++r) {
                    const int j = j0 + wm * 32 + m * 16 + fk * 4 + r;
                    const float v = acc[m][n][r];
                    const ushort h = f2bf(v);
                    MTh[(size_t)j * F + i] = h;
                    MTl[(size_t)j * F + i] = f2bf(v - bf2f(h));
                }
        }
    } else if (pb < 24) {
        // WvT[j][k] = Wv[k][j], split hi/lo (64x64 LDS transpose, 256 thr)
        float (*t)[65] = (float(*)[65])smem;
        const int tb = pb - 8;
        const int jt = (tb & 3) * 64, kt = (tb >> 2) * 64;
        const int lkb = tid >> 3, lj = (tid & 7) * 8;
#pragma unroll
        for (int u2 = 0; u2 < 2; ++u2) {
            const int lk = lkb + u2 * 32;
            const float* p = &Wv[(size_t)(kt + lk) * E + jt + lj];
            const float4 v0 = *reinterpret_cast<const float4*>(p);
            const float4 v1 = *reinterpret_cast<const float4*>(p + 4);
            t[lk][lj + 0] = v0.x; t[lk][lj + 1] = v0.y; t[lk][lj + 2] = v0.z; t[lk][lj + 3] = v0.w;
            t[lk][lj + 4] = v1.x; t[lk][lj + 5] = v1.y; t[lk][lj + 6] = v1.z; t[lk][lj + 7] = v1.w;
        }
        __syncthreads();
#pragma unroll
        for (int u2 = 0; u2 < 2; ++u2) {
            const int oj = lkb + u2 * 32;
            const int ok = lj;
            ushort h[8], l[8];
#pragma unroll
            for (int u = 0; u < 8; ++u) {
                const float v = t[ok + u][oj];
                h[u] = f2bf(v); l[u] = f2bf(v - bf2f(h[u]));
            }
            *reinterpret_cast<uint4*>(&WvTh[(size_t)(jt + oj) * F + kt + ok]) = pack8(h);
            *reinterpret_cast<uint4*>(&WvTl[(size_t)(jt + oj) * F + kt + ok]) = pack8(l);
        }
    } else if (pb < 32) {
        // c[j] = Wk_j . bq (32 j per block)
        float* bqs = (float*)smem;
        bqs[tid] = bq[tid];
        __syncthreads();
        const float4 b4 = *reinterpret_cast<const float4*>(&bqs[lane * 4]);
#pragma unroll
        for (int i = 0; i < 8; ++i) {
            const int j = (pb - 24) * 32 + wave * 8 + i;
            const float4 k4 = *reinterpret_cast<const float4*>(&Wk[(size_t)j * F + lane * 4]);
            float p = k4.x * b4.x + k4.y * b4.y + k4.z * b4.z + k4.w * b4.w;
#pragma unroll
            for (int off = 32; off; off >>= 1) p += __shfl_xor(p, off);
            if (lane == 0) cbuf[j] = p;
        }
    }
    gbar(&bar[0]);

    // ---------------- phase 1: q~ = gather @ MT + c ----------------
    for (int vb = pb; vb < QVB; vb += NGRID)
        gemm_vb(vb, id2feat, nodes, MTh, MTl, cbuf, qtm, B, smem, tid, wave, fr, fk);
    gbar(&bar[1]);

    // ---------------- phase 2: gather (proven config, triple-buffered:
    //                  12 row-loads in flight to offset 12-vs-19.5 waves/CU) --
    for (int vb = pb; vb < GVB; vb += NGRID) {
        const int node = vb * 4 + wave;
        if (node < B) {
            const int idxv = neigh[node * S + (lane & (S - 1))];
            const float4 qv = *reinterpret_cast<const float4*>(&qtm[(size_t)node * F + lane * 4]);
            float m = -INFINITY, l = 0.f;
            float4 a = make_float4(0.f, 0.f, 0.f, 0.f);
            float4 va[CH], vb2[CH], vc[CH];
            ld_chunk(va, idxv, 0, id2feat, lane);
            ld_chunk(vb2, idxv, 4, id2feat, lane);
            ld_chunk(vc, idxv, 8, id2feat, lane);
            proc_chunk(va, qv, m, l, a);
            ld_chunk(va, idxv, 12, id2feat, lane);
            proc_chunk(vb2, qv, m, l, a);
            ld_chunk(vb2, idxv, 16, id2feat, lane);
            proc_chunk(vc, qv, m, l, a);
            ld_chunk(vc, idxv, 20, id2feat, lane);
            proc_chunk(va, qv, m, l, a);
            ld_chunk(va, idxv, 24, id2feat, lane);
            proc_chunk(vb2, qv, m, l, a);
            ld_chunk(vb2, idxv, 28, id2feat, lane);
            proc_chunk(vc, qv, m, l, a);
            proc_chunk(va, qv, m, l, a);
            proc_chunk(vb2, qv, m, l, a);
            const float inv = 1.0f / l;
            float4 o;
            o.x = a.x * inv; o.y = a.y * inv; o.z = a.z * inv; o.w = a.w * inv;
            *reinterpret_cast<float4*>(&qtm[(size_t)node * F + lane * 4]) = o;
        }
    }
    gbar(&bar[2]);

    // ---------------- phase 3: out = m @ WvT + bv ----------------
    for (int vb = pb; vb < QVB; vb += NGRID)
        gemm_vb(vb, qtm, nullptr, WvTh, WvTl, bv, out, B, smem, tid, wave, fr, fk);
}

// ---------------------------------------------------------------------------
extern "C" void kernel_launch(void* const* d_in, const int* in_sizes, int n_in,
                              void* d_out, int out_size, void* d_ws, size_t ws_size,
                              hipStream_t stream) {
    const int*   nodes   = (const int*)d_in[0];
    const int*   neigh   = (const int*)d_in[1];
    const float* id2feat = (const float*)d_in[2];
    const float* Wq      = (const float*)d_in[3];
    const float* bq      = (const float*)d_in[4];
    const float* Wk      = (const float*)d_in[5];
    // d_in[6] = bk unused: softmax-invariant (self column masked).
    const float* Wv      = (const float*)d_in[7];
    const float* bv      = (const float*)d_in[8];
    float* out = (float*)d_out;
    int B = in_sizes[0];

    // workspace layout: [barriers 64B][MTh][MTl][WvTh][WvTl][cbuf][qtm]
    uint*   bar  = (uint*)d_ws;
    ushort* MTh  = (ushort*)((char*)d_ws + 64);
    ushort* MTl  = MTh + 65536;
    ushort* WvTh = MTl + 65536;
    ushort* WvTl = WvTh + 65536;
    float*  cbuf = (float*)(WvTl + 65536);
    float*  qtm  = cbuf + 256;

    // zero the barrier counters (fresh every launch; graph-capture legal)
    hipMemsetAsync(bar, 0, 64, stream);
    pipeline<<<dim3(NGRID), dim3(256), 0, stream>>>(nodes, neigh, id2feat,
                                                    Wq, bq, Wk, Wv, bv, out,
                                                    bar, MTh, MTl, WvTh, WvTl,
                                                    cbuf, qtm, B);
}

// Round 15
// 118.676 us; speedup vs baseline: 4.8331x; 3.1135x over previous
//
#include <hip/hip_runtime.h>
#include <math.h>

#define F 256
#define E 256
#define S 32
#define CH 4

typedef __attribute__((ext_vector_type(8))) short short8;
typedef __attribute__((ext_vector_type(4))) float f32x4;

__device__ __forceinline__ ushort f2bf(float x) {
    uint u = __float_as_uint(x);
    return (ushort)((u + 0x7fffu + ((u >> 16) & 1u)) >> 16);
}
__device__ __forceinline__ float bf2f(ushort h) {
    return __uint_as_float(((uint)h) << 16);
}
__device__ __forceinline__ uint4 pack8(const ushort* h) {
    uint4 r;
    r.x = (uint)h[0] | ((uint)h[1] << 16); r.y = (uint)h[2] | ((uint)h[3] << 16);
    r.z = (uint)h[4] | ((uint)h[5] << 16); r.w = (uint)h[6] | ((uint)h[7] << 16);
    return r;
}
__device__ __forceinline__ void split4(const float* x, uint2& ph, uint2& pl) {
    ushort h[4], l[4];
#pragma unroll
    for (int i = 0; i < 4; ++i) { h[i] = f2bf(x[i]); l[i] = f2bf(x[i] - bf2f(h[i])); }
    ph.x = (uint)h[0] | ((uint)h[1] << 16); ph.y = (uint)h[2] | ((uint)h[3] << 16);
    pl.x = (uint)l[0] | ((uint)l[1] << 16); pl.y = (uint)l[2] | ((uint)l[3] << 16);
}
__device__ __forceinline__ void split8(const float* x, short8& h, short8& l) {
    ushort hh[8], ll[8];
#pragma unroll
    for (int i = 0; i < 8; ++i) { hh[i] = f2bf(x[i]); ll[i] = f2bf(x[i] - bf2f(hh[i])); }
    uint4 ph = pack8(hh), pl = pack8(ll);
    h = *reinterpret_cast<short8*>(&ph);
    l = *reinterpret_cast<short8*>(&pl);
}

// ---------------------------------------------------------------------------
// prep (proven): blocks 0..3 -> MT[j][i] = Wk_j . Wq_i (bf16x3 MFMA from
// global), split hi/lo; blocks 4..19 -> WvT transpose/split; 20..23 -> c.
// ---------------------------------------------------------------------------
__global__ __launch_bounds__(512) void prep(const float* __restrict__ Wq,
                                            const float* __restrict__ bq,
                                            const float* __restrict__ Wk,
                                            const float* __restrict__ Wv,
                                            ushort* __restrict__ MTh,
                                            ushort* __restrict__ MTl,
                                            ushort* __restrict__ WvTh,
                                            ushort* __restrict__ WvTl,
                                            float* __restrict__ c) {
    const int blk = blockIdx.x, tid = threadIdx.x;
    const int lane = tid & 63, wave = tid >> 6;
    if (blk < 4) {
        const int wm = wave >> 2, wn = wave & 3;
        const int fr = lane & 15, fk = lane >> 4;
        const int j0 = blk * 64;
        f32x4 acc[2][4];
#pragma unroll
        for (int m = 0; m < 2; ++m)
#pragma unroll
            for (int n = 0; n < 4; ++n) acc[m][n] = (f32x4){0.f, 0.f, 0.f, 0.f};
        for (int k0 = 0; k0 < F; k0 += 32) {
            short8 ah[2], al[2];
#pragma unroll
            for (int m = 0; m < 2; ++m) {
                const float* p = &Wk[(size_t)(j0 + wm * 32 + m * 16 + fr) * F + k0 + fk * 8];
                float x[8];
                *reinterpret_cast<float4*>(&x[0]) = *reinterpret_cast<const float4*>(p);
                *reinterpret_cast<float4*>(&x[4]) = *reinterpret_cast<const float4*>(p + 4);
                split8(x, ah[m], al[m]);
            }
#pragma unroll
            for (int n = 0; n < 4; ++n) {
                const float* p = &Wq[(size_t)(wn * 64 + n * 16 + fr) * F + k0 + fk * 8];
                float x[8];
                *reinterpret_cast<float4*>(&x[0]) = *reinterpret_cast<const float4*>(p);
                *reinterpret_cast<float4*>(&x[4]) = *reinterpret_cast<const float4*>(p + 4);
                short8 bh, bl;
                split8(x, bh, bl);
#pragma unroll
                for (int m = 0; m < 2; ++m) {
                    acc[m][n] = __builtin_amdgcn_mfma_f32_16x16x32_bf16(ah[m], bh, acc[m][n], 0, 0, 0);
                    acc[m][n] = __builtin_amdgcn_mfma_f32_16x16x32_bf16(ah[m], bl, acc[m][n], 0, 0, 0);
                    acc[m][n] = __builtin_amdgcn_mfma_f32_16x16x32_bf16(al[m], bh, acc[m][n], 0, 0, 0);
                }
            }
        }
#pragma unroll
        for (int n = 0; n < 4; ++n) {
            const int i = wn * 64 + n * 16 + fr;
#pragma unroll
            for (int m = 0; m < 2; ++m)
#pragma unroll
                for (int r = 0; r < 4; ++r) {
                    const int j = j0 + wm * 32 + m * 16 + fk * 4 + r;
                    const float v = acc[m][n][r];
                    const ushort h = f2bf(v);
                    MTh[(size_t)j * F + i] = h;
                    MTl[(size_t)j * F + i] = f2bf(v - bf2f(h));
                }
        }
    } else if (blk < 20) {
        __shared__ float t[64][65];
        const int tb = blk - 4;
        const int jt = (tb & 3) * 64, kt = (tb >> 2) * 64;
        const int lk = tid >> 3, lj = (tid & 7) * 8;
        {
            const float* p = &Wv[(size_t)(kt + lk) * E + jt + lj];
            const float4 v0 = *reinterpret_cast<const float4*>(p);
            const float4 v1 = *reinterpret_cast<const float4*>(p + 4);
            t[lk][lj + 0] = v0.x; t[lk][lj + 1] = v0.y; t[lk][lj + 2] = v0.z; t[lk][lj + 3] = v0.w;
            t[lk][lj + 4] = v1.x; t[lk][lj + 5] = v1.y; t[lk][lj + 6] = v1.z; t[lk][lj + 7] = v1.w;
        }
        __syncthreads();
        const int oj = tid >> 3, ok = (tid & 7) * 8;
        ushort h[8], l[8];
#pragma unroll
        for (int u = 0; u < 8; ++u) {
            const float v = t[ok + u][oj];
            h[u] = f2bf(v); l[u] = f2bf(v - bf2f(h[u]));
        }
        *reinterpret_cast<uint4*>(&WvTh[(size_t)(jt + oj) * F + kt + ok]) = pack8(h);
        *reinterpret_cast<uint4*>(&WvTl[(size_t)(jt + oj) * F + kt + ok]) = pack8(l);
    } else {
        __shared__ float bqs[F];
        if (tid < F) bqs[tid] = bq[tid];
        __syncthreads();
        const float4 b4 = *reinterpret_cast<const float4*>(&bqs[lane * 4]);
#pragma unroll
        for (int i = 0; i < 8; ++i) {
            const int j = (blk - 20) * 64 + wave * 8 + i;
            const float4 k4 = *reinterpret_cast<const float4*>(&Wk[(size_t)j * F + lane * 4]);
            float p = k4.x * b4.x + k4.y * b4.y + k4.z * b4.z + k4.w * b4.w;
#pragma unroll
            for (int off = 32; off; off >>= 1) p += __shfl_xor(p, off);
            if (lane == 0) c[j] = p;
        }
    }
}

// ---------------------------------------------------------------------------
// gemm32: out[r][:] = X[idx?idx[r]:r][:] @ BT(hi/lo) + bias, f32 out.
// BM=32, BN=128, BK=32, 256 thr = 4 waves. Grid (ceil(rows/32), 2).
// A double-buffered in LDS (one barrier/iter); B fragments straight from the
// L2-hot split tables (64B/row contiguous per fragment read).
// ---------------------------------------------------------------------------
__global__ __launch_bounds__(256) void gemm32(const float* __restrict__ X,
                                              const int* __restrict__ idx,
                                              const ushort* __restrict__ BTh,
                                              const ushort* __restrict__ BTl,
                                              const float* __restrict__ bias,
                                              float* __restrict__ outp,
                                              int rows) {
    __shared__ ushort Ah[2][32][40], Al[2][32][40];
    const int tid = threadIdx.x, lane = tid & 63, wave = tid >> 6;
    const int fr = lane & 15, fk = lane >> 4;
    const int row0 = blockIdx.x * 32;
    const int col0 = blockIdx.y * 128 + wave * 32;

    const int arL = tid >> 3, akL = (tid & 7) * 4;
    const int gr = row0 + arL;
    const int grc = gr < rows ? gr : rows - 1;
    const long arow = idx ? (long)idx[grc] : (long)grc;
    const float* aptr = X + arow * (long)F + akL;

    f32x4 acc[2][2];
#pragma unroll
    for (int m = 0; m < 2; ++m)
#pragma unroll
        for (int n = 0; n < 2; ++n) acc[m][n] = (f32x4){0.f, 0.f, 0.f, 0.f};

    {
        const float4 av = *reinterpret_cast<const float4*>(aptr);
        uint2 h, l; split4(&av.x, h, l);
        *reinterpret_cast<uint2*>(&Ah[0][arL][akL]) = h;
        *reinterpret_cast<uint2*>(&Al[0][arL][akL]) = l;
    }
    __syncthreads();

    for (int t = 0; t < 8; ++t) {
        const int cur = t & 1;
        float4 nv;
        if (t < 7) nv = *reinterpret_cast<const float4*>(aptr + (t + 1) * 32);

        short8 a_h[2], a_l[2];
#pragma unroll
        for (int m = 0; m < 2; ++m) {
            a_h[m] = *reinterpret_cast<const short8*>(&Ah[cur][m * 16 + fr][fk * 8]);
            a_l[m] = *reinterpret_cast<const short8*>(&Al[cur][m * 16 + fr][fk * 8]);
        }
#pragma unroll
        for (int n = 0; n < 2; ++n) {
            const size_t boff = (size_t)(col0 + n * 16 + fr) * F + t * 32 + fk * 8;
            const short8 bh = *reinterpret_cast<const short8*>(&BTh[boff]);
            const short8 bl = *reinterpret_cast<const short8*>(&BTl[boff]);
#pragma unroll
            for (int m = 0; m < 2; ++m) {
                acc[m][n] = __builtin_amdgcn_mfma_f32_16x16x32_bf16(a_h[m], bh, acc[m][n], 0, 0, 0);
                acc[m][n] = __builtin_amdgcn_mfma_f32_16x16x32_bf16(a_h[m], bl, acc[m][n], 0, 0, 0);
                acc[m][n] = __builtin_amdgcn_mfma_f32_16x16x32_bf16(a_l[m], bh, acc[m][n], 0, 0, 0);
            }
        }
        if (t < 7) {
            uint2 h, l; split4(&nv.x, h, l);
            *reinterpret_cast<uint2*>(&Ah[cur ^ 1][arL][akL]) = h;
            *reinterpret_cast<uint2*>(&Al[cur ^ 1][arL][akL]) = l;
        }
        __syncthreads();
    }

#pragma unroll
    for (int n = 0; n < 2; ++n) {
        const int col = col0 + n * 16 + fr;
        const float cc = bias[col];
#pragma unroll
        for (int m = 0; m < 2; ++m)
#pragma unroll
            for (int r = 0; r < 4; ++r) {
                const int row = row0 + m * 16 + fk * 4 + r;
                if (row < rows) outp[(size_t)row * F + col] = acc[m][n][r] + cc;
            }
    }
}

// ---------------------------------------------------------------------------
// attn_gather (PROVEN 60.5 us config, R3): one wave per node, single-pass
// online softmax, 4-row double-buffered chunks, m written back to qtm.
// Pinned at the random-gather memory wall (~2.7 TB/s HBM) — three different
// structures (LDS-staged, 32-deep MLP, this) all land at 60.5 us.
// ---------------------------------------------------------------------------
__device__ __forceinline__ void ld_chunk(float4* d, int idxv, int s0,
                                         const float* __restrict__ t, int lane) {
#pragma unroll
    for (int j = 0; j < CH; ++j) {
        const int nid = __builtin_amdgcn_readlane(idxv, s0 + j);
        d[j] = *reinterpret_cast<const float4*>(&t[(size_t)nid * F + lane * 4]);
    }
}
__device__ __forceinline__ void proc_chunk(const float4* v, const float4 qv,
                                           float& m, float& l, float4& acc) {
#pragma unroll
    for (int j = 0; j < CH; ++j) {
        float p = v[j].x * qv.x + v[j].y * qv.y + v[j].z * qv.z + v[j].w * qv.w;
#pragma unroll
        for (int off = 32; off; off >>= 1) p += __shfl_xor(p, off);
        if (p <= m) {
            const float w = __expf(p - m);
            l += w;
            acc.x += w * v[j].x; acc.y += w * v[j].y;
            acc.z += w * v[j].z; acc.w += w * v[j].w;
        } else {
            const float cc = __expf(m - p);
            l = l * cc + 1.f;
            acc.x = acc.x * cc + v[j].x; acc.y = acc.y * cc + v[j].y;
            acc.z = acc.z * cc + v[j].z; acc.w = acc.w * cc + v[j].w;
            m = p;
        }
    }
}

__global__ __launch_bounds__(256) void attn_gather(const int* __restrict__ neigh_idx,
                                                   const float* __restrict__ id2feat,
                                                   float* __restrict__ qtm,
                                                   int B) {
    const int node = blockIdx.x * 4 + (threadIdx.x >> 6);
    const int lane = threadIdx.x & 63;
    if (node >= B) return;

    const int idxv = neigh_idx[node * S + (lane & (S - 1))];
    const float4 qv = *reinterpret_cast<const float4*>(&qtm[(size_t)node * F + lane * 4]);

    float m = -INFINITY, l = 0.f;
    float4 acc = make_float4(0.f, 0.f, 0.f, 0.f);

    float4 va[CH], vb[CH];
    ld_chunk(va, idxv, 0, id2feat, lane);
    ld_chunk(vb, idxv, 4, id2feat, lane);
    proc_chunk(va, qv, m, l, acc);
    ld_chunk(va, idxv, 8, id2feat, lane);
    proc_chunk(vb, qv, m, l, acc);
    ld_chunk(vb, idxv, 12, id2feat, lane);
    proc_chunk(va, qv, m, l, acc);
    ld_chunk(va, idxv, 16, id2feat, lane);
    proc_chunk(vb, qv, m, l, acc);
    ld_chunk(vb, idxv, 20, id2feat, lane);
    proc_chunk(va, qv, m, l, acc);
    ld_chunk(va, idxv, 24, id2feat, lane);
    proc_chunk(vb, qv, m, l, acc);
    ld_chunk(vb, idxv, 28, id2feat, lane);
    proc_chunk(va, qv, m, l, acc);
    proc_chunk(vb, qv, m, l, acc);

    const float inv = 1.0f / l;
    float4 o;
    o.x = acc.x * inv; o.y = acc.y * inv; o.z = acc.z * inv; o.w = acc.w * inv;
    *reinterpret_cast<float4*>(&qtm[(size_t)node * F + lane * 4]) = o;
}

// ---------------------------------------------------------------------------
extern "C" void kernel_launch(void* const* d_in, const int* in_sizes, int n_in,
                              void* d_out, int out_size, void* d_ws, size_t ws_size,
                              hipStream_t stream) {
    const int*   nodes   = (const int*)d_in[0];
    const int*   neigh   = (const int*)d_in[1];
    const float* id2feat = (const float*)d_in[2];
    const float* Wq      = (const float*)d_in[3];
    const float* bq      = (const float*)d_in[4];
    const float* Wk      = (const float*)d_in[5];
    // d_in[6] = bk unused: softmax-invariant (self column masked).
    const float* Wv      = (const float*)d_in[7];
    const float* bv      = (const float*)d_in[8];
    float* out = (float*)d_out;
    const int B = in_sizes[0];

    ushort* MTh  = (ushort*)d_ws;            // 65536 ushorts each
    ushort* MTl  = MTh + 65536;
    ushort* WvTh = MTl + 65536;
    ushort* WvTl = WvTh + 65536;
    float*  cbuf = (float*)(WvTl + 65536);   // 256 f32
    float*  qtm  = cbuf + 256;               // [B][F] f32: q~, then m (in place)

    // 1) tables
    prep<<<dim3(24), dim3(512), 0, stream>>>(Wq, bq, Wk, Wv, MTh, MTl, WvTh, WvTl, cbuf);
    // 2) q~ = gather(id2feat, nodes) @ MT + c
    gemm32<<<dim3((B + 31) / 32, 2), dim3(256), 0, stream>>>(id2feat, nodes,
                                                             MTh, MTl, cbuf, qtm, B);
    // 3) scores -> softmax -> m (in place over qtm), proven standalone config
    attn_gather<<<dim3((B + 3) / 4), dim3(256), 0, stream>>>(neigh, id2feat, qtm, B);
    // 4) out = m @ WvT + bv (full hi/lo accuracy)
    gemm32<<<dim3((B + 31) / 32, 2), dim3(256), 0, stream>>>(qtm, nullptr,
                                                             WvTh, WvTl, bv, out, B);
}